// Round 1
// baseline (40.017 us; speedup 1.0000x reference)
//
#include <hip/hip_runtime.h>

// Problem constants (fixed by setup_inputs):
// root_positions:          [B=16, T_IN=64, 3]        f32
// joint_rotations_ortho6d: [B=16, T_IN=64, N=52, 6]  f32
// input_frame_indices:     [64] int (sorted, idx[0]=0)
// target_frame_indices:    [4096] int (arange, unused — implied)
// Outputs (concatenated): jp [B, 4160, N, 3] then jr [B, 4160, N, 6], f32
constexpr int B     = 16;
constexpr int T_IN  = 64;
constexpr int NJ    = 52;
constexpr int T_OUT = 4096;
constexpr int T_PAD = T_OUT + T_IN;      // 63 front pad + T_OUT + 1 back pad = 4160

constexpr int JP_ROW  = NJ * 3;          // 156 floats per (b, t) row
constexpr int JR_ROW  = NJ * 6;          // 312 floats per (b, t) row
constexpr int JP_ROW4 = JP_ROW / 4;      // 39 float4
constexpr int JR_ROW4 = JR_ROW / 4;      // 78 float4

__global__ __launch_bounds__(128) void ZeroVelocityWrapper_38482906972738_kernel(
    const float* __restrict__ root,   // [B, T_IN, 3]
    const float* __restrict__ rot,    // [B, T_IN, NJ, 6]
    const int*   __restrict__ idx,    // [T_IN] sorted
    float*       __restrict__ out)
{
    const int row   = blockIdx.x;            // row = b * T_PAD + s_out
    const int b     = row / T_PAD;
    const int s_out = row - b * T_PAD;
    int s = s_out - (T_IN - 1);              // undo front pad
    s = s < 0 ? 0 : (s > T_OUT - 1 ? T_OUT - 1 : s);

    __shared__ int   sh_lo, sh_k;
    __shared__ float sh_r[3];

    if (threadIdx.x == 0) {
        // upper_bound: first t with idx[t] > s  (guaranteed >=1 since idx[0]=0)
        int lo = 0, hi = T_IN;
        while (lo < hi) { int mid = (lo + hi) >> 1; if (idx[mid] <= s) lo = mid + 1; else hi = mid; }
        const int ub = lo;
        const int m  = idx[ub - 1];          // nearest past keyframe value
        // lower_bound of m in [0, ub): first occurrence of the tied value
        int lo2 = 0, hi2 = ub - 1;
        while (lo2 < hi2) { int mid = (lo2 + hi2) >> 1; if (idx[mid] < m) lo2 = mid + 1; else hi2 = mid; }
        const int k = ub - lo2;
        sh_lo = lo2;
        sh_k  = k;
        const float inv = 1.0f / (float)k;
        float r0 = 0.f, r1 = 0.f, r2 = 0.f;
        const float* rp = root + (size_t)(b * T_IN + lo2) * 3;
        for (int t = 0; t < k; ++t) { r0 += rp[0]; r1 += rp[1]; r2 += rp[2]; rp += 3; }
        sh_r[0] = r0 * inv; sh_r[1] = r1 * inv; sh_r[2] = r2 * inv;
    }
    __syncthreads();

    const int   lo  = sh_lo;
    const int   k   = sh_k;
    const float inv = 1.0f / (float)k;
    const int   tid = threadIdx.x;

    float4*       jp  = (float4*)out + (size_t)row * JP_ROW4;
    float4*       jr  = (float4*)(out + (size_t)B * T_PAD * JP_ROW) + (size_t)row * JR_ROW4;
    const float4* src = (const float4*)rot + (size_t)(b * T_IN + lo) * JR_ROW4;

    if (tid < JP_ROW4) {
        // joint_positions: root mean broadcast across joints; pattern period 3
        const int base = tid * 4;
        float4 v;
        v.x = sh_r[(base + 0) % 3];
        v.y = sh_r[(base + 1) % 3];
        v.z = sh_r[(base + 2) % 3];
        v.w = sh_r[(base + 3) % 3];
        jp[tid] = v;
    } else if (tid < JP_ROW4 + JR_ROW4) {
        // joint_rotations: mean over the k tied input frames (k==1 almost always)
        const int w = tid - JP_ROW4;
        float4 acc = src[w];
        for (int t = 1; t < k; ++t) {
            const float4 v = src[(size_t)t * JR_ROW4 + w];
            acc.x += v.x; acc.y += v.y; acc.z += v.z; acc.w += v.w;
        }
        acc.x *= inv; acc.y *= inv; acc.z *= inv; acc.w *= inv;
        jr[w] = acc;
    }
}

extern "C" void kernel_launch(void* const* d_in, const int* in_sizes, int n_in,
                              void* d_out, int out_size, void* d_ws, size_t ws_size,
                              hipStream_t stream) {
    const float* root = (const float*)d_in[0];
    const float* rot  = (const float*)d_in[1];
    const int*   idx  = (const int*)d_in[2];
    // d_in[3] = target_frame_indices (arange(T_OUT)) — implied by the mapping, unused.
    float* out = (float*)d_out;

    const int grid = B * T_PAD;   // one block per (b, s_out) row-pair
    hipLaunchKernelGGL(ZeroVelocityWrapper_38482906972738_kernel,
                       dim3(grid), dim3(128), 0, stream,
                       root, rot, idx, out);
}

// Round 2
// 30.460 us; speedup vs baseline: 1.3138x; 1.3138x over previous
//
#include <hip/hip_runtime.h>

// Problem constants (fixed by setup_inputs):
// root_positions:          [B=16, T_IN=64, 3]        f32
// joint_rotations_ortho6d: [B=16, T_IN=64, N=52, 6]  f32
// input_frame_indices:     [64] int (sorted, idx[0]=0)
// target_frame_indices:    [4096] arange (implied, unused)
// Outputs (concat): jp [B, 4160, N, 3] then jr [B, 4160, N, 6], f32
constexpr int B     = 16;
constexpr int T_IN  = 64;
constexpr int NJ    = 52;
constexpr int T_OUT = 4096;
constexpr int T_PAD = T_OUT + T_IN;       // 4160

constexpr int JP_ROW4 = NJ * 3 / 4;       // 39 float4 per row
constexpr int JR_ROW4 = NJ * 6 / 4;       // 78 float4 per row
constexpr int NROWS   = B * T_PAD;        // 66,560
constexpr int NP4     = NROWS * JP_ROW4;  // 2,595,840
constexpr int NR4     = NROWS * JR_ROW4;  // 5,191,680
constexpr int TOTAL4  = NP4 + NR4;        // 7,787,520

// ws layout: float4 rootmean[NROWS] | int4 sel[T_PAD] {lo, k, bits(1/k), 0}
constexpr size_t WS_NEED = (size_t)NROWS * 16 + (size_t)T_PAD * 16;

// ---------------- Kernel A: per-row selection + root mean (tiny) ----------------
__global__ __launch_bounds__(256) void zv_precomp(
    const float* __restrict__ root, const int* __restrict__ idx,
    float4* __restrict__ rootmean, int4* __restrict__ sel)
{
    __shared__ int sidx[T_IN];
    if (threadIdx.x < T_IN) sidx[threadIdx.x] = idx[threadIdx.x];
    __syncthreads();

    const int row = blockIdx.x * 256 + threadIdx.x;
    if (row >= NROWS) return;
    const int b     = row / T_PAD;
    const int s_out = row - b * T_PAD;
    int s = s_out - (T_IN - 1);
    s = s < 0 ? 0 : (s > T_OUT - 1 ? T_OUT - 1 : s);

    // upper_bound: first t with idx[t] > s (>=1 since idx[0]=0)
    int lo = 0, hi = T_IN;
    while (lo < hi) { int mid = (lo + hi) >> 1; if (sidx[mid] <= s) lo = mid + 1; else hi = mid; }
    const int ub = lo;
    const int m  = sidx[ub - 1];
    int lo2 = 0, hi2 = ub - 1;
    while (lo2 < hi2) { int mid = (lo2 + hi2) >> 1; if (sidx[mid] < m) lo2 = mid + 1; else hi2 = mid; }
    const int   k   = ub - lo2;
    const float inv = 1.0f / (float)k;

    float r0 = 0.f, r1 = 0.f, r2 = 0.f;
    const float* rp = root + (size_t)(b * T_IN + lo2) * 3;
    for (int t = 0; t < k; ++t) { r0 += rp[0]; r1 += rp[1]; r2 += rp[2]; rp += 3; }
    rootmean[row] = make_float4(r0 * inv, r1 * inv, r2 * inv, 0.f);
    if (row < T_PAD)  // b == 0 covers every s_out exactly once
        sel[row] = make_int4(lo2, k, __float_as_int(inv), 0);
}

// ---------------- Kernel B: pure streaming store, 1 float4 per thread ----------------
__global__ __launch_bounds__(256) void zv_store(
    const float* __restrict__ rot, const float4* __restrict__ rootmean,
    const int4* __restrict__ sel, float4* __restrict__ out4)
{
    const int i = blockIdx.x * 256 + threadIdx.x;
    if (i >= TOTAL4) return;

    if (i < NP4) {
        const int row = i / JP_ROW4;
        const int w   = i - row * JP_ROW4;
        const float4 rm = rootmean[row];
        const int m = w % 3;          // (4w) mod 3 == w mod 3
        const float x0 = (m == 0) ? rm.x : ((m == 1) ? rm.y : rm.z);
        const float x1 = (m == 0) ? rm.y : ((m == 1) ? rm.z : rm.x);
        const float x2 = (m == 0) ? rm.z : ((m == 1) ? rm.x : rm.y);
        out4[i] = make_float4(x0, x1, x2, x0);
    } else {
        const int j   = i - NP4;
        const int row = j / JR_ROW4;
        const int w   = j - row * JR_ROW4;
        const int b     = row / T_PAD;
        const int s_out = row - b * T_PAD;
        const int4 lk = sel[s_out];
        const float4* src = (const float4*)rot + ((size_t)(b * T_IN + lk.x) * JR_ROW4 + w);
        float4 acc = src[0];
        if (lk.y > 1) {
            for (int t = 1; t < lk.y; ++t) {
                const float4 v = src[(size_t)t * JR_ROW4];
                acc.x += v.x; acc.y += v.y; acc.z += v.z; acc.w += v.w;
            }
            const float inv = __int_as_float(lk.z);
            acc.x *= inv; acc.y *= inv; acc.z *= inv; acc.w *= inv;
        }
        out4[i] = acc;
    }
}

// ---------------- Fallback (no-ws path): round-1 kernel, known-correct ----------------
__global__ __launch_bounds__(128) void zv_fallback(
    const float* __restrict__ root, const float* __restrict__ rot,
    const int* __restrict__ idx, float* __restrict__ out)
{
    const int row   = blockIdx.x;
    const int b     = row / T_PAD;
    const int s_out = row - b * T_PAD;
    int s = s_out - (T_IN - 1);
    s = s < 0 ? 0 : (s > T_OUT - 1 ? T_OUT - 1 : s);

    __shared__ int   sh_lo, sh_k;
    __shared__ float sh_r[3];
    if (threadIdx.x == 0) {
        int lo = 0, hi = T_IN;
        while (lo < hi) { int mid = (lo + hi) >> 1; if (idx[mid] <= s) lo = mid + 1; else hi = mid; }
        const int ub = lo;
        const int m  = idx[ub - 1];
        int lo2 = 0, hi2 = ub - 1;
        while (lo2 < hi2) { int mid = (lo2 + hi2) >> 1; if (idx[mid] < m) lo2 = mid + 1; else hi2 = mid; }
        const int k = ub - lo2;
        sh_lo = lo2; sh_k = k;
        const float inv = 1.0f / (float)k;
        float r0 = 0.f, r1 = 0.f, r2 = 0.f;
        const float* rp = root + (size_t)(b * T_IN + lo2) * 3;
        for (int t = 0; t < k; ++t) { r0 += rp[0]; r1 += rp[1]; r2 += rp[2]; rp += 3; }
        sh_r[0] = r0 * inv; sh_r[1] = r1 * inv; sh_r[2] = r2 * inv;
    }
    __syncthreads();
    const int lo = sh_lo, k = sh_k, tid = threadIdx.x;
    const float inv = 1.0f / (float)k;
    float4*       jp  = (float4*)out + (size_t)row * JP_ROW4;
    float4*       jr  = (float4*)(out + (size_t)NROWS * NJ * 3) + (size_t)row * JR_ROW4;
    const float4* src = (const float4*)rot + (size_t)(b * T_IN + lo) * JR_ROW4;
    if (tid < JP_ROW4) {
        const int base = tid * 4;
        float4 v;
        v.x = sh_r[(base + 0) % 3]; v.y = sh_r[(base + 1) % 3];
        v.z = sh_r[(base + 2) % 3]; v.w = sh_r[(base + 3) % 3];
        jp[tid] = v;
    } else if (tid < JP_ROW4 + JR_ROW4) {
        const int w = tid - JP_ROW4;
        float4 acc = src[w];
        for (int t = 1; t < k; ++t) {
            const float4 v = src[(size_t)t * JR_ROW4 + w];
            acc.x += v.x; acc.y += v.y; acc.z += v.z; acc.w += v.w;
        }
        acc.x *= inv; acc.y *= inv; acc.z *= inv; acc.w *= inv;
        jr[w] = acc;
    }
}

extern "C" void kernel_launch(void* const* d_in, const int* in_sizes, int n_in,
                              void* d_out, int out_size, void* d_ws, size_t ws_size,
                              hipStream_t stream) {
    const float* root = (const float*)d_in[0];
    const float* rot  = (const float*)d_in[1];
    const int*   idx  = (const int*)d_in[2];
    float* out = (float*)d_out;

    if (ws_size >= WS_NEED && d_ws != nullptr) {
        float4* rootmean = (float4*)d_ws;
        int4*   sel      = (int4*)((char*)d_ws + (size_t)NROWS * 16);
        hipLaunchKernelGGL(zv_precomp, dim3((NROWS + 255) / 256), dim3(256), 0, stream,
                           root, idx, rootmean, sel);
        hipLaunchKernelGGL(zv_store, dim3((TOTAL4 + 255) / 256), dim3(256), 0, stream,
                           rot, rootmean, sel, (float4*)out);
    } else {
        hipLaunchKernelGGL(zv_fallback, dim3(NROWS), dim3(128), 0, stream,
                           root, rot, idx, out);
    }
}

// Round 5
// 27.978 us; speedup vs baseline: 1.4303x; 1.0887x over previous
//
#include <hip/hip_runtime.h>

// Problem constants (fixed by setup_inputs):
// root_positions:          [B=16, T_IN=64, 3]        f32
// joint_rotations_ortho6d: [B=16, T_IN=64, N=52, 6]  f32
// input_frame_indices:     [64] int (sorted, idx[0]=0)
// target_frame_indices:    [4096] arange (implied, unused)
// Outputs (concat): jp [B, 4160, N, 3] then jr [B, 4160, N, 6], f32
constexpr int B     = 16;
constexpr int T_IN  = 64;
constexpr int NJ    = 52;
constexpr int T_OUT = 4096;
constexpr int T_PAD = T_OUT + T_IN;       // 4160

constexpr int JP_ROW4 = NJ * 3 / 4;       // 39 float4 per jp row
constexpr int JR_ROW4 = NJ * 6 / 4;       // 78 float4 per jr row
constexpr int NROWS   = B * T_PAD;        // 66,560
constexpr int NP4     = NROWS * JP_ROW4;  // 2,595,840
constexpr int NR4     = NROWS * JR_ROW4;  // 5,191,680
constexpr int TOTAL4  = NP4 + NR4;        // 7,787,520 (= 256 * 30,420 exactly)

typedef float f4 __attribute__((ext_vector_type(4)));  // native vector: OK for nontemporal builtins

// Single fused kernel: 1 thread = 1 output float4. Each thread derives the
// nearest-past-keyframe run [lo, lo+k) itself via two unrolled branchless
// binary searches over the LDS-cached 64-entry sorted index array. All
// selection work hides under the HBM store stream (store-bound kernel).
__global__ __launch_bounds__(256) void zv_fused(
    const float* __restrict__ root,   // [B, T_IN, 3]
    const float* __restrict__ rot,    // [B, T_IN, NJ, 6]
    const int*   __restrict__ idx,    // [T_IN] sorted, idx[0]=0
    f4*          __restrict__ out4)
{
    __shared__ int sidx[T_IN];
    if (threadIdx.x < T_IN) sidx[threadIdx.x] = idx[threadIdx.x];
    __syncthreads();

    const int i = blockIdx.x * 256 + threadIdx.x;
    if (i >= TOTAL4) return;

    const bool is_jp = (i < NP4);
    int row, w;
    if (is_jp) {
        row = i / JP_ROW4;  w = i - row * JP_ROW4;
    } else {
        const int j = i - NP4;
        row = j / JR_ROW4;  w = j - row * JR_ROW4;
    }
    const int b     = row / T_PAD;
    const int s_out = row - b * T_PAD;
    int s = s_out - (T_IN - 1);                       // undo front pad
    s = s < 0 ? 0 : (s > T_OUT - 1 ? T_OUT - 1 : s);

    // ub = count of idx[t] <= s, in [1, 64] (idx[0]=0 guarantees >=1).
    // NOTE: step sequence must start at 64 (with bounds guard) so ub==64 is
    // reachable — steps 32+16+...+1 max out at 63, which mis-selected the
    // tail frames (s >= idx[63]) in the previous round.
    int ub = 0;
    #pragma unroll
    for (int step = 64; step > 0; step >>= 1)
        if (ub + step <= T_IN && sidx[ub + step - 1] <= s) ub += step;
    const int m = sidx[ub - 1];                       // nearest past keyframe value
    // lo = count of idx[t] < m; m is present at position ub-1, so lo <= 63
    // and the 32..1 sequence suffices.
    int lo = 0;
    #pragma unroll
    for (int step = 32; step > 0; step >>= 1)
        if (sidx[lo + step - 1] < m) lo += step;
    const int   k   = ub - lo;                        // run length (k==1 almost always)
    const float inv = 1.0f / (float)k;

    if (is_jp) {
        // joint_positions: mean of root over the run, broadcast across joints.
        const float* rp = root + (size_t)(b * T_IN + lo) * 3;
        float r0 = rp[0], r1 = rp[1], r2 = rp[2];
        for (int t = 1; t < k; ++t) { r0 += rp[3*t]; r1 += rp[3*t+1]; r2 += rp[3*t+2]; }
        r0 *= inv; r1 *= inv; r2 *= inv;
        const int md = w % 3;                         // (4w) mod 3 == w mod 3
        const float x0 = md == 0 ? r0 : (md == 1 ? r1 : r2);
        const float x1 = md == 0 ? r1 : (md == 1 ? r2 : r0);
        const float x2 = md == 0 ? r2 : (md == 1 ? r0 : r1);
        f4 v; v.x = x0; v.y = x1; v.z = x2; v.w = x0;
        __builtin_nontemporal_store(v, &out4[i]);
    } else {
        // joint_rotations: mean over the run; rot is 1.2 MB -> L2-resident gather.
        const f4* src = (const f4*)rot + ((size_t)(b * T_IN + lo) * JR_ROW4 + w);
        f4 acc = src[0];
        if (k > 1) {
            for (int t = 1; t < k; ++t) acc += src[(size_t)t * JR_ROW4];
            acc *= inv;
        }
        __builtin_nontemporal_store(acc, &out4[i]);
    }
}

extern "C" void kernel_launch(void* const* d_in, const int* in_sizes, int n_in,
                              void* d_out, int out_size, void* d_ws, size_t ws_size,
                              hipStream_t stream) {
    const float* root = (const float*)d_in[0];
    const float* rot  = (const float*)d_in[1];
    const int*   idx  = (const int*)d_in[2];
    // d_in[3] = target_frame_indices (arange) — implied by the mapping, unused.
    f4* out4 = (f4*)d_out;

    const int grid = (TOTAL4 + 255) / 256;   // 30,420 blocks, exact
    hipLaunchKernelGGL(zv_fused, dim3(grid), dim3(256), 0, stream,
                       root, rot, idx, out4);
}